// Round 16
// baseline (160.310 us; speedup 1.0000x reference)
//
#include <hip/hip_runtime.h>
#include <hip/hip_fp16.h>
#include <math.h>

// Hasegawa-Wakatani 2D RHS, 2048^2, all-spectral. Round 16 = R15 (159.8us,
// best) + ONE change: k_inv4 uses fp16 LDS (__half2 per cplx, 32KB/block):
//  - 4 blocks/CU (32-wave cap, was 16) -> 2x barrier overlap
//  - loads/stores move raw fp16 bits (no convert); stages convert in-reg
//  - bank pattern under the existing XOR swizzle verified conflict-free-ish
// Everything else byte-identical to R15.
//
// Pipeline (slots of 33.5MB in d_ws):
//  pack_T : n,w --fftY(r16), write^T--> W[ky][x] fp16            slot0
//  unpackS: W row --fftX(r8), unpack--> S1..S4 (fp16, 1/N)       slot1,2
//  inv4   : S_i --ifftX(r16,fp16 LDS), write^T--> T_i fp16       slot3,4
//  bracket: T1..T3 rows --4x fft(r8)--> BR fp16 (my-skip)        d_out
//  slabX  : BR --fftX(r16), mask/N, ifftX(r16), write^T--> ADVt  slot1
//  final  : ADVt,T4 rows --2x ifft(r8), combine--> dn,dw f32     d_out

#define NF 2048
#define HALF 1024
#define K0F 0.15f
#define DEAL_LIM 682

typedef float2 cplx;
typedef __half2 ch;

__device__ __forceinline__ ch toh(cplx v){ return __float22half2_rn(make_float2(v.x, v.y)); }
__device__ __forceinline__ cplx toc(ch h){ float2 f = __half22float2(h); return make_float2(f.x, f.y); }

__device__ __forceinline__ int sw(int i){ return i ^ ((i>>4)&15) ^ ((i>>8)&15); }
__device__ __forceinline__ cplx cmul(cplx a, cplx b){ return make_float2(a.x*b.x - a.y*b.y, a.x*b.y + a.y*b.x); }
__device__ __forceinline__ cplx cadd(cplx a, cplx b){ return make_float2(a.x+b.x, a.y+b.y); }
__device__ __forceinline__ cplx csub(cplx a, cplx b){ return make_float2(a.x-b.x, a.y-b.y); }
template<int SIGN> __device__ __forceinline__ cplx rot90(cplx z){
  return (SIGN>0)? make_float2(-z.y,z.x) : make_float2(z.y,-z.x); }
__device__ __forceinline__ void lput(cplx* L, int i, cplx v){ L[sw(i)] = v; }
__device__ __forceinline__ cplx lget(const cplx* L, int i){ return L[sw(i)]; }

__device__ __forceinline__ int xcd_chunk(int bid, int nwg){
  return (bid & 7) * (nwg >> 3) + (bid >> 3);
}

// ================= radix-8,8,8,4 core (TPR parametric) =====================
template<int SIGN, int TPR, int M>
__device__ __forceinline__ void stage8_ip(cplx* X, int t) {
  constexpr int BPT = 256 / TPR;
  const float ang = (float)SIGN * 0.0030679615757712824f; // 2*pi/2048
  cplx a[BPT][8];
#pragma unroll
  for (int u = 0; u < BPT; ++u) {
    const int b = t + u * TPR;
#pragma unroll
    for (int k = 0; k < 8; ++k) a[u][k] = X[sw(b + 256 * k)];
  }
  __syncthreads();
#pragma unroll
  for (int u = 0; u < BPT; ++u) {
    const int b = t + u * TPR;
    const int i = b & (M - 1);
    const int jm = b - i;
    cplx a0=a[u][0], a1=a[u][1], a2=a[u][2], a3=a[u][3],
         a4=a[u][4], a5=a[u][5], a6=a[u][6], a7=a[u][7];
    cplx t0=cadd(a0,a4), t1=csub(a0,a4), t2=cadd(a2,a6), t3=rot90<SIGN>(csub(a2,a6));
    cplx E0=cadd(t0,t2), E2=csub(t0,t2), E1=cadd(t1,t3), E3=csub(t1,t3);
    cplx u0=cadd(a1,a5), u1=csub(a1,a5), u2=cadd(a3,a7), u3=rot90<SIGN>(csub(a3,a7));
    cplx O0=cadd(u0,u2), O2=csub(u0,u2), O1=cadd(u1,u3), O3=csub(u1,u3);
    const float hh = 0.70710678118654752440f;
    O1 = cmul(O1, make_float2(hh, (float)SIGN*hh));
    O2 = rot90<SIGN>(O2);
    O3 = cmul(O3, make_float2(-hh, (float)SIGN*hh));
    cplx y0=cadd(E0,O0), y4=csub(E0,O0);
    cplx y1=cadd(E1,O1), y5=csub(E1,O1);
    cplx y2=cadd(E2,O2), y6=csub(E2,O2);
    cplx y3=cadd(E3,O3), y7=csub(E3,O3);
    float sn, cs;
    __sincosf(ang * (float)jm, &sn, &cs);
    cplx w1 = make_float2(cs, sn);
    cplx w2 = cmul(w1,w1), w3 = cmul(w2,w1), w4 = cmul(w2,w2);
    cplx w5 = cmul(w3,w2), w6 = cmul(w3,w3), w7 = cmul(w4,w3);
    const int o = 8*jm + i;
    X[sw(o)]       = y0;
    X[sw(o+M)]     = cmul(y1,w1);
    X[sw(o+2*M)]   = cmul(y2,w2);
    X[sw(o+3*M)]   = cmul(y3,w3);
    X[sw(o+4*M)]   = cmul(y4,w4);
    X[sw(o+5*M)]   = cmul(y5,w5);
    X[sw(o+6*M)]   = cmul(y6,w6);
    X[sw(o+7*M)]   = cmul(y7,w7);
  }
  __syncthreads();
}

template<int SIGN, int TPR>
__device__ __forceinline__ void stage4_ip(cplx* X, int t){
  constexpr int QPT = 512 / TPR;
  cplx a[QPT][4];
#pragma unroll
  for (int u=0; u<QPT; ++u){
    const int b = t + u*TPR;
#pragma unroll
    for (int k=0;k<4;++k) a[u][k] = X[sw(b + 512*k)];
  }
  __syncthreads();
#pragma unroll
  for (int u=0; u<QPT; ++u){
    const int b = t + u*TPR;
    cplx a0=a[u][0], a1=a[u][1], a2=a[u][2], a3=a[u][3];
    cplx t0=cadd(a0,a2), t1=csub(a0,a2), t2=cadd(a1,a3), t3=rot90<SIGN>(csub(a1,a3));
    X[sw(b)]       = cadd(t0,t2);
    X[sw(b+512)]   = cadd(t1,t3);
    X[sw(b+1024)]  = csub(t0,t2);
    X[sw(b+1536)]  = csub(t1,t3);
  }
  __syncthreads();
}

template<int SIGN, int TPR>
__device__ __forceinline__ void fft_ip(cplx* X, int t){
  __syncthreads();
  stage8_ip<SIGN,TPR,1>(X,t);
  stage8_ip<SIGN,TPR,8>(X,t);
  stage8_ip<SIGN,TPR,64>(X,t);
  stage4_ip<SIGN,TPR>(X,t);
}

// ================= radix-16,16,8 core (TPR=128, f32 LDS) ===================
template<int SIGN>
__device__ __forceinline__ void dft4(cplx& a0, cplx& a1, cplx& a2, cplx& a3){
  cplx t0=cadd(a0,a2), t1=csub(a0,a2), t2=cadd(a1,a3), t3=rot90<SIGN>(csub(a1,a3));
  a0=cadd(t0,t2); a1=cadd(t1,t3); a2=csub(t0,t2); a3=csub(t1,t3);
}

// 16-pt DFT via 4x4 DIT. In: a[n] natural. Out: y[q] at a[4*(q&3)+(q>>2)].
template<int SIGN>
__device__ __forceinline__ void dft16(cplx a[16]){
  dft4<SIGN>(a[0], a[4], a[8],  a[12]);
  dft4<SIGN>(a[1], a[5], a[9],  a[13]);
  dft4<SIGN>(a[2], a[6], a[10], a[14]);
  dft4<SIGN>(a[3], a[7], a[11], a[15]);
  const float c1 = 0.92387953251128675613f, s1v = 0.38268343236508977173f;
  const float hh = 0.70710678118654752440f;
  const cplx e1 = make_float2(c1,  (float)SIGN*s1v);   // w16^1
  const cplx e2 = make_float2(hh,  (float)SIGN*hh);    // w16^2
  const cplx e3 = make_float2(s1v, (float)SIGN*c1);    // w16^3
  const cplx e6 = make_float2(-hh, (float)SIGN*hh);    // w16^6
  a[5]  = cmul(a[5],  e1);
  a[6]  = cmul(a[6],  e2);
  a[7]  = cmul(a[7],  e3);
  a[9]  = cmul(a[9],  e2);
  a[10] = rot90<SIGN>(a[10]);
  a[11] = cmul(a[11], e6);
  a[13] = cmul(a[13], e3);
  a[14] = cmul(a[14], e6);
  { cplx m = cmul(a[15], e1); a[15] = make_float2(-m.x, -m.y); }
  dft4<SIGN>(a[0],  a[1],  a[2],  a[3]);
  dft4<SIGN>(a[4],  a[5],  a[6],  a[7]);
  dft4<SIGN>(a[8],  a[9],  a[10], a[11]);
  dft4<SIGN>(a[12], a[13], a[14], a[15]);
}

// computes w1..w15 for this thread's jm and applies output permutation+store
// via the macro-free helpers below (kept inline in each stage variant).

// radix-16 Stockham stage, 128 butterflies, t in 0..127 (one per lane).
template<int SIGN, int M>
__device__ __forceinline__ void stage16_ip(cplx* X, int t){
  const float ang = (float)SIGN * 0.0030679615757712824f; // 2*pi/2048
  cplx a[16];
#pragma unroll
  for (int k=0;k<16;++k) a[k] = X[sw(t + 128*k)];
  __syncthreads();
  dft16<SIGN>(a);
  const int i = t & (M-1);
  const int jm = t - i;
  float sn, cs;
  __sincosf(ang * (float)jm, &sn, &cs);
  cplx w1 = make_float2(cs, sn);
  cplx w2 = cmul(w1,w1),  w3 = cmul(w2,w1),  w4 = cmul(w2,w2);
  cplx w5 = cmul(w3,w2),  w6 = cmul(w3,w3),  w7 = cmul(w4,w3);
  cplx w8 = cmul(w4,w4),  w9 = cmul(w5,w4),  w10= cmul(w5,w5);
  cplx w11= cmul(w6,w5),  w12= cmul(w6,w6),  w13= cmul(w7,w6);
  cplx w14= cmul(w7,w7),  w15= cmul(w8,w7);
  const int o = 16*jm + i;
  X[sw(o)]      = a[0];
  X[sw(o+M)]    = cmul(a[4],  w1);
  X[sw(o+2*M)]  = cmul(a[8],  w2);
  X[sw(o+3*M)]  = cmul(a[12], w3);
  X[sw(o+4*M)]  = cmul(a[1],  w4);
  X[sw(o+5*M)]  = cmul(a[5],  w5);
  X[sw(o+6*M)]  = cmul(a[9],  w6);
  X[sw(o+7*M)]  = cmul(a[13], w7);
  X[sw(o+8*M)]  = cmul(a[2],  w8);
  X[sw(o+9*M)]  = cmul(a[6],  w9);
  X[sw(o+10*M)] = cmul(a[10], w10);
  X[sw(o+11*M)] = cmul(a[14], w11);
  X[sw(o+12*M)] = cmul(a[3],  w12);
  X[sw(o+13*M)] = cmul(a[7],  w13);
  X[sw(o+14*M)] = cmul(a[11], w14);
  X[sw(o+15*M)] = cmul(a[15], w15);
  __syncthreads();
}

// final radix-8 stage, m=256 (jm=0, twiddle-free), t in 0..127, 2 bfly/lane
template<int SIGN>
__device__ __forceinline__ void stage8_last16(cplx* X, int t){
  cplx a[2][8];
#pragma unroll
  for (int u=0; u<2; ++u){
    const int b = t + u*128;
#pragma unroll
    for (int k=0;k<8;++k) a[u][k] = X[sw(b + 256*k)];
  }
  __syncthreads();
#pragma unroll
  for (int u=0; u<2; ++u){
    const int b = t + u*128;
    cplx a0=a[u][0], a1=a[u][1], a2=a[u][2], a3=a[u][3],
         a4=a[u][4], a5=a[u][5], a6=a[u][6], a7=a[u][7];
    cplx t0=cadd(a0,a4), t1=csub(a0,a4), t2=cadd(a2,a6), t3=rot90<SIGN>(csub(a2,a6));
    cplx E0=cadd(t0,t2), E2=csub(t0,t2), E1=cadd(t1,t3), E3=csub(t1,t3);
    cplx u0=cadd(a1,a5), u1=csub(a1,a5), u2=cadd(a3,a7), u3=rot90<SIGN>(csub(a3,a7));
    cplx O0=cadd(u0,u2), O2=csub(u0,u2), O1=cadd(u1,u3), O3=csub(u1,u3);
    const float hh = 0.70710678118654752440f;
    O1 = cmul(O1, make_float2(hh, (float)SIGN*hh));
    O2 = rot90<SIGN>(O2);
    O3 = cmul(O3, make_float2(-hh, (float)SIGN*hh));
    X[sw(b)]       = cadd(E0,O0);
    X[sw(b+256)]   = cadd(E1,O1);
    X[sw(b+512)]   = cadd(E2,O2);
    X[sw(b+768)]   = cadd(E3,O3);
    X[sw(b+1024)]  = csub(E0,O0);
    X[sw(b+1280)]  = csub(E1,O1);
    X[sw(b+1536)]  = csub(E2,O2);
    X[sw(b+1792)]  = csub(E3,O3);
  }
  __syncthreads();
}

template<int SIGN>
__device__ __forceinline__ void fft16_ip(cplx* X, int t){
  __syncthreads();
  stage16_ip<SIGN,1>(X,t);
  stage16_ip<SIGN,16>(X,t);
  stage8_last16<SIGN>(X,t);
}

// ================= radix-16,16,8 core, fp16 LDS variant (inv4 only) ========
template<int SIGN, int M>
__device__ __forceinline__ void stage16h_ip(ch* X, int t){
  const float ang = (float)SIGN * 0.0030679615757712824f; // 2*pi/2048
  cplx a[16];
#pragma unroll
  for (int k=0;k<16;++k) a[k] = toc(X[sw(t + 128*k)]);
  __syncthreads();
  dft16<SIGN>(a);
  const int i = t & (M-1);
  const int jm = t - i;
  float sn, cs;
  __sincosf(ang * (float)jm, &sn, &cs);
  cplx w1 = make_float2(cs, sn);
  cplx w2 = cmul(w1,w1),  w3 = cmul(w2,w1),  w4 = cmul(w2,w2);
  cplx w5 = cmul(w3,w2),  w6 = cmul(w3,w3),  w7 = cmul(w4,w3);
  cplx w8 = cmul(w4,w4),  w9 = cmul(w5,w4),  w10= cmul(w5,w5);
  cplx w11= cmul(w6,w5),  w12= cmul(w6,w6),  w13= cmul(w7,w6);
  cplx w14= cmul(w7,w7),  w15= cmul(w8,w7);
  const int o = 16*jm + i;
  X[sw(o)]      = toh(a[0]);
  X[sw(o+M)]    = toh(cmul(a[4],  w1));
  X[sw(o+2*M)]  = toh(cmul(a[8],  w2));
  X[sw(o+3*M)]  = toh(cmul(a[12], w3));
  X[sw(o+4*M)]  = toh(cmul(a[1],  w4));
  X[sw(o+5*M)]  = toh(cmul(a[5],  w5));
  X[sw(o+6*M)]  = toh(cmul(a[9],  w6));
  X[sw(o+7*M)]  = toh(cmul(a[13], w7));
  X[sw(o+8*M)]  = toh(cmul(a[2],  w8));
  X[sw(o+9*M)]  = toh(cmul(a[6],  w9));
  X[sw(o+10*M)] = toh(cmul(a[10], w10));
  X[sw(o+11*M)] = toh(cmul(a[14], w11));
  X[sw(o+12*M)] = toh(cmul(a[3],  w12));
  X[sw(o+13*M)] = toh(cmul(a[7],  w13));
  X[sw(o+14*M)] = toh(cmul(a[11], w14));
  X[sw(o+15*M)] = toh(cmul(a[15], w15));
  __syncthreads();
}

template<int SIGN>
__device__ __forceinline__ void stage8h_last16(ch* X, int t){
  cplx a[2][8];
#pragma unroll
  for (int u=0; u<2; ++u){
    const int b = t + u*128;
#pragma unroll
    for (int k=0;k<8;++k) a[u][k] = toc(X[sw(b + 256*k)]);
  }
  __syncthreads();
#pragma unroll
  for (int u=0; u<2; ++u){
    const int b = t + u*128;
    cplx a0=a[u][0], a1=a[u][1], a2=a[u][2], a3=a[u][3],
         a4=a[u][4], a5=a[u][5], a6=a[u][6], a7=a[u][7];
    cplx t0=cadd(a0,a4), t1=csub(a0,a4), t2=cadd(a2,a6), t3=rot90<SIGN>(csub(a2,a6));
    cplx E0=cadd(t0,t2), E2=csub(t0,t2), E1=cadd(t1,t3), E3=csub(t1,t3);
    cplx u0=cadd(a1,a5), u1=csub(a1,a5), u2=cadd(a3,a7), u3=rot90<SIGN>(csub(a3,a7));
    cplx O0=cadd(u0,u2), O2=csub(u0,u2), O1=cadd(u1,u3), O3=csub(u1,u3);
    const float hh = 0.70710678118654752440f;
    O1 = cmul(O1, make_float2(hh, (float)SIGN*hh));
    O2 = rot90<SIGN>(O2);
    O3 = cmul(O3, make_float2(-hh, (float)SIGN*hh));
    X[sw(b)]       = toh(cadd(E0,O0));
    X[sw(b+256)]   = toh(cadd(E1,O1));
    X[sw(b+512)]   = toh(cadd(E2,O2));
    X[sw(b+768)]   = toh(cadd(E3,O3));
    X[sw(b+1024)]  = toh(csub(E0,O0));
    X[sw(b+1280)]  = toh(csub(E1,O1));
    X[sw(b+1536)]  = toh(csub(E2,O2));
    X[sw(b+1792)]  = toh(csub(E3,O3));
  }
  __syncthreads();
}

template<int SIGN>
__device__ __forceinline__ void fft16h_ip(ch* X, int t){
  __syncthreads();
  stage16h_ip<SIGN,1>(X,t);
  stage16h_ip<SIGN,16>(X,t);
  stage8h_last16<SIGN>(X,t);
}

// ---- spectral unpack at one (kx,ky): a=F(ky,kx), b=F(-ky,-kx)
__device__ __forceinline__ void unpack_point(cplx a, cplx b,
    float kxv, float kyv, float kxp, float kyp,
    cplx& s1, cplx& s2, cplx& s3, cplx& s4) {
  cplx nh = make_float2(0.5f*(a.x + b.x),  0.5f*(a.y - b.y));
  cplx wh = make_float2(0.5f*(a.y + b.y), -0.5f*(a.x - b.x));
  float k2 = kxv*kxv + kyv*kyv;
  float pinv = (k2 > 1e-12f) ? (-1.0f/k2) : 0.0f;
  cplx ph = make_float2(wh.x*pinv, wh.y*pinv);
  s1 = make_float2(-kxp*ph.y - kyp*ph.x, kxp*ph.x - kyp*ph.y);
  s2 = make_float2(-kxp*nh.y - kyp*nh.x, kxp*nh.x - kyp*nh.y);
  s3 = make_float2(-kxp*wh.y - kyp*wh.x, kxp*wh.x - kyp*wh.y);
  float dnc = 0.001f * k2;
  cplx Ln = make_float2( kyp*ph.y + (ph.x - nh.x) - dnc*nh.x,
                        -kyp*ph.x + (ph.y - nh.y) - dnc*nh.y);
  cplx Lw = make_float2( kyp*nh.y + (ph.x - nh.x) - dnc*wh.x,
                        -kyp*nh.x + (ph.y - nh.y) - dnc*wh.y);
  s4 = make_float2(Ln.x - Lw.y, Ln.y + Lw.x);
}

// ---- kernels -------------------------------------------------------------

// 4 x-rows: load n,w, fft along y (r16), transposed fp16 store -> W[ky][x]
__global__ void __launch_bounds__(512) k_fwd_pack_T(const float* __restrict__ nIn,
                                                    const float* __restrict__ wIn,
                                                    ch* __restrict__ out) {
  __shared__ cplx L[4*NF];
  const int tid = threadIdx.x;
  const int lb = xcd_chunk(blockIdx.x, gridDim.x);
  const int xb = lb*4;
#pragma unroll
  for (int u=0; u<4; ++u){
    int f = tid + u*512;           // 0..2047
    int r = f >> 9;                // row 0..3
    int p = f & 511;               // float4 idx
    float4 nv = ((const float4*)(nIn + (size_t)(xb+r)*NF))[p];
    float4 wv = ((const float4*)(wIn + (size_t)(xb+r)*NF))[p];
    cplx* Lr = L + r*NF;
    lput(Lr, 4*p+0, make_float2(nv.x, wv.x));
    lput(Lr, 4*p+1, make_float2(nv.y, wv.y));
    lput(Lr, 4*p+2, make_float2(nv.z, wv.z));
    lput(Lr, 4*p+3, make_float2(nv.w, wv.w));
  }
  const int row = tid >> 7, t = tid & 127;
  fft16_ip<-1>(L + row*NF, t);
  uint4* o16 = (uint4*)out;        // fp16 row = 512 uint4
#pragma unroll
  for (int u=0; u<4; ++u){
    int ky = tid + u*512;          // 0..2047
    ch h0 = toh(lget(L + 0*NF, ky));
    ch h1 = toh(lget(L + 1*NF, ky));
    ch h2 = toh(lget(L + 2*NF, ky));
    ch h3 = toh(lget(L + 3*NF, ky));
    uint4 v;
    v.x = *(unsigned*)&h0; v.y = *(unsigned*)&h1;
    v.z = *(unsigned*)&h2; v.w = *(unsigned*)&h3;
    o16[(size_t)ky*(NF/4) + lb] = v;
  }
}

// rows kyA=b, kyB=(b==0?1024:2048-b): fftX (r8) both, unpack -> S1..S4 fp16
__global__ void __launch_bounds__(512) k_unpackS(const ch* __restrict__ in,
                                                 ch* __restrict__ S1, ch* __restrict__ S2,
                                                 ch* __restrict__ S3, ch* __restrict__ S4) {
  __shared__ cplx F0[NF], F1[NF];
  const int tid = threadIdx.x;
  const int b = xcd_chunk(blockIdx.x, gridDim.x);   // 0..1023
  const int kyA = b;
  const int kyB = (b == 0) ? HALF : NF - b;
  const int half = tid >> 8;
  const int t = tid & 255;
  cplx* Fm = half ? F1 : F0;
  {
    const ch* g = in + (size_t)(half ? kyB : kyA)*NF;
#pragma unroll
    for (int u=0; u<2; ++u){
      int p = t + u*256;           // uint4 idx, 512 per fp16 row
      uint4 v = ((const uint4*)g)[p];
      lput(Fm, 4*p+0, toc(*(ch*)&v.x));
      lput(Fm, 4*p+1, toc(*(ch*)&v.y));
      lput(Fm, 4*p+2, toc(*(ch*)&v.z));
      lput(Fm, 4*p+3, toc(*(ch*)&v.w));
    }
    fft_ip<-1,256>(Fm, t);
  }
  const cplx* Fp = (b == 0) ? (const cplx*)Fm : (half ? F0 : F1);
  const int kyM = half ? kyB : kyA;
  const int sy = (kyM < HALF) ? kyM : kyM - NF;
  const float kyv = K0F * (float)sy;
  const float kyp = (kyM == HALF) ? 0.0f : kyv;
  const float sc = 1.0f/(float)NF;
  const size_t rbase = (size_t)kyM * NF;
#pragma unroll
  for (int u=0; u<8; ++u){
    int kx = t + u*256;
    int kx2 = (NF - kx) & (NF - 1);
    int sx = (kx < HALF) ? kx : kx - NF;
    float kxv = K0F * (float)sx;
    float kxp = (kx == HALF) ? 0.0f : kxv;
    cplx s1,s2,s3,s4;
    unpack_point(lget(Fm,kx), lget(Fp,kx2), kxv, kyv, kxp, kyp, s1,s2,s3,s4);
    S1[rbase+kx] = toh(make_float2(sc*s1.x, sc*s1.y));
    S2[rbase+kx] = toh(make_float2(sc*s2.x, sc*s2.y));
    S3[rbase+kx] = toh(make_float2(sc*s3.x, sc*s3.y));
    S4[rbase+kx] = toh(make_float2(sc*s4.x, sc*s4.y));
  }
}

// 4 rows, one of 4 arrays (blockIdx.y): ifft (r16, fp16 LDS 32KB),
// transposed fp16 store. Loads/stores move raw fp16 bits.
__global__ void __launch_bounds__(512) k_inv4(const ch* __restrict__ S1, const ch* __restrict__ S2,
                                              const ch* __restrict__ S3, const ch* __restrict__ S4,
                                              ch* __restrict__ T1, ch* __restrict__ T2,
                                              ch* __restrict__ T3, ch* __restrict__ T4) {
  __shared__ ch Lh[4*NF];          // 32 KB
  const int tid = threadIdx.x;
  const int lb = xcd_chunk(blockIdx.x, gridDim.x);
  const ch* in; ch* out;
  if      (blockIdx.y == 0){ in = S1; out = T1; }
  else if (blockIdx.y == 1){ in = S2; out = T2; }
  else if (blockIdx.y == 2){ in = S3; out = T3; }
  else                     { in = S4; out = T4; }
  const int rb = lb*4;
#pragma unroll
  for (int u=0; u<4; ++u){
    int f = tid + u*512;           // 0..2047
    int r = f >> 9, p = f & 511;   // 512 uint4 per fp16 row
    uint4 v = ((const uint4*)(in + (size_t)(rb+r)*NF))[p];
    ch* Lr = Lh + r*NF;
    Lr[sw(4*p+0)] = *(ch*)&v.x;
    Lr[sw(4*p+1)] = *(ch*)&v.y;
    Lr[sw(4*p+2)] = *(ch*)&v.z;
    Lr[sw(4*p+3)] = *(ch*)&v.w;
  }
  const int row = tid >> 7, t = tid & 127;
  fft16h_ip<1>(Lh + row*NF, t);
  uint4* o16 = (uint4*)out;        // fp16 row = 512 uint4
#pragma unroll
  for (int u=0; u<4; ++u){
    int q = tid + u*512;           // output row (= x) 0..2047
    ch h0 = Lh[0*NF + sw(q)];
    ch h1 = Lh[1*NF + sw(q)];
    ch h2 = Lh[2*NF + sw(q)];
    ch h3 = Lh[3*NF + sw(q)];
    uint4 v;
    v.x = *(unsigned*)&h0; v.y = *(unsigned*)&h1;
    v.z = *(unsigned*)&h2; v.w = *(unsigned*)&h3;
    o16[(size_t)q*(NF/4) + lb] = v;
  }
}

// 1 x-row, 256 thr (r8): 3x ifft (dphi regs), bracket, fwd fft -> BR fp16
__global__ void __launch_bounds__(256) k_bracket(const ch* __restrict__ T1,
                                                 const ch* __restrict__ T2,
                                                 const ch* __restrict__ T3,
                                                 ch* __restrict__ out) {
  __shared__ cplx A[NF];
  const int t = threadIdx.x;
  const size_t base = (size_t)blockIdx.x * NF;
#pragma unroll
  for (int u=0; u<2; ++u){
    int p = t + u*256;
    uint4 v = ((const uint4*)(T1 + base))[p];
    lput(A, 4*p+0, toc(*(ch*)&v.x)); lput(A, 4*p+1, toc(*(ch*)&v.y));
    lput(A, 4*p+2, toc(*(ch*)&v.z)); lput(A, 4*p+3, toc(*(ch*)&v.w));
  }
  fft_ip<1,256>(A, t);                  // (dphix,dphiy)*N
  cplx dphi[8];
#pragma unroll
  for (int u=0; u<8; ++u) dphi[u] = lget(A, t + u*256);
  __syncthreads();
#pragma unroll
  for (int u=0; u<2; ++u){
    int p = t + u*256;
    uint4 v = ((const uint4*)(T2 + base))[p];
    lput(A, 4*p+0, toc(*(ch*)&v.x)); lput(A, 4*p+1, toc(*(ch*)&v.y));
    lput(A, 4*p+2, toc(*(ch*)&v.z)); lput(A, 4*p+3, toc(*(ch*)&v.w));
  }
  fft_ip<1,256>(A, t);                  // (dnx,dny)*N
  float jn[8];
#pragma unroll
  for (int u=0; u<8; ++u){
    cplx dd = lget(A, t + u*256);
    jn[u] = dphi[u].x*dd.y - dphi[u].y*dd.x;
  }
  __syncthreads();
#pragma unroll
  for (int u=0; u<2; ++u){
    int p = t + u*256;
    uint4 v = ((const uint4*)(T3 + base))[p];
    lput(A, 4*p+0, toc(*(ch*)&v.x)); lput(A, 4*p+1, toc(*(ch*)&v.y));
    lput(A, 4*p+2, toc(*(ch*)&v.z)); lput(A, 4*p+3, toc(*(ch*)&v.w));
  }
  fft_ip<1,256>(A, t);                  // (dwx,dwy)*N
  const float sc2 = 1.0f/((float)NF*(float)NF);
#pragma unroll
  for (int u=0; u<8; ++u){
    int c = t + u*256;
    cplx dd = lget(A, c);
    float jw = dphi[u].x*dd.y - dphi[u].y*dd.x;
    lput(A, c, make_float2(sc2*jn[u], sc2*jw));   // own-slot r/w
  }
  fft_ip<-1,256>(A, t);                 // fft(j_n + i*j_w) along y
  uint4* o16 = (uint4*)(out + base);
#pragma unroll
  for (int u=0; u<2; ++u){
    int p = t + u*256;                  // uint4 covers ky' 4p..4p+3
    if (p <= 170 || p >= 341) {         // skip fully-masked [684,1363]
      ch h0 = toh(lget(A, 4*p+0));
      ch h1 = toh(lget(A, 4*p+1));
      ch h2 = toh(lget(A, 4*p+2));
      ch h3 = toh(lget(A, 4*p+3));
      uint4 v;
      v.x = *(unsigned*)&h0; v.y = *(unsigned*)&h1;
      v.z = *(unsigned*)&h2; v.w = *(unsigned*)&h3;
      o16[p] = v;
    }
  }
}

// 4 ky'-columns: fftX(r16), 2/3 mask*(1/N), ifftX(r16), transposed fp16 write.
// Fully-masked slabs: nothing at all (final synthesizes their zeros).
__global__ void __launch_bounds__(512) k_slabX(const ch* __restrict__ in,
                                               ch* __restrict__ out) {
  __shared__ cplx L[4*NF];
  const int tid = threadIdx.x;
  const int lb = xcd_chunk(blockIdx.x, gridDim.x);
  const int cb = lb*4;
  if (cb >= 684 && cb <= 1360) return;  // masked: not written, not read
#pragma unroll
  for (int u=0; u<4; ++u){
    int x = tid + u*512;           // 0..2047
    uint4 v = *(const uint4*)(in + (size_t)x*NF + cb);
    lput(L + 0*NF, x, toc(*(ch*)&v.x));
    lput(L + 1*NF, x, toc(*(ch*)&v.y));
    lput(L + 2*NF, x, toc(*(ch*)&v.z));
    lput(L + 3*NF, x, toc(*(ch*)&v.w));
  }
  const int row = tid >> 7, t = tid & 127;
  fft16_ip<-1>(L + row*NF, t);
  const float sc = 1.0f/(float)NF;
#pragma unroll
  for (int v2=0; v2<16; ++v2){
    int g = tid + v2*512;          // 0..8191
    int c = g >> 11, kk = g & 2047;
    int ky = cb + c;
    int sy = (ky < HALF) ? ky : ky - NF;
    int sx = (kk < HALF) ? kk : kk - NF;
    float m = (((sy<0?-sy:sy) <= DEAL_LIM) && ((sx<0?-sx:sx) <= DEAL_LIM)) ? sc : 0.0f;
    cplx z = lget(L + c*NF, kk);
    lput(L + c*NF, kk, make_float2(m*z.x, m*z.y));   // own-slot r/w
  }
  fft16_ip<1>(L + row*NF, t);
#pragma unroll
  for (int u=0; u<4; ++u){
    int x = tid + u*512;
    ch h0 = toh(lget(L + 0*NF, x));
    ch h1 = toh(lget(L + 1*NF, x));
    ch h2 = toh(lget(L + 2*NF, x));
    ch h3 = toh(lget(L + 3*NF, x));
    uint4 v;
    v.x = *(unsigned*)&h0; v.y = *(unsigned*)&h1;
    v.z = *(unsigned*)&h2; v.w = *(unsigned*)&h3;
    *(uint4*)(out + (size_t)x*NF + cb) = v;
  }
}

// 1 x-row, 256 thr (r8): ifft ADVt (adv regs; zeros synthesized for the
// masked range), ifft T4, combine -> dn,dw (f32)
__global__ void __launch_bounds__(256) k_final(const ch* __restrict__ ADVt,
                                               const ch* __restrict__ T4,
                                               float* __restrict__ outF) {
  __shared__ cplx A[NF];
  const int t = threadIdx.x;
  const size_t base = (size_t)blockIdx.x * NF;
#pragma unroll
  for (int u=0; u<2; ++u){
    int p = t + u*256;
    if (p >= 171 && p <= 340) {         // ky' 684..1363: slabX wrote nothing
      cplx z = make_float2(0.f, 0.f);
      lput(A, 4*p+0, z); lput(A, 4*p+1, z);
      lput(A, 4*p+2, z); lput(A, 4*p+3, z);
    } else {
      uint4 v = ((const uint4*)(ADVt + base))[p];
      lput(A, 4*p+0, toc(*(ch*)&v.x)); lput(A, 4*p+1, toc(*(ch*)&v.y));
      lput(A, 4*p+2, toc(*(ch*)&v.z)); lput(A, 4*p+3, toc(*(ch*)&v.w));
    }
  }
  fft_ip<1,256>(A, t);                  // adv*N
  cplx adv[8];
#pragma unroll
  for (int u=0; u<8; ++u) adv[u] = lget(A, t + u*256);
  __syncthreads();
#pragma unroll
  for (int u=0; u<2; ++u){
    int p = t + u*256;
    uint4 v = ((const uint4*)(T4 + base))[p];
    lput(A, 4*p+0, toc(*(ch*)&v.x)); lput(A, 4*p+1, toc(*(ch*)&v.y));
    lput(A, 4*p+2, toc(*(ch*)&v.z)); lput(A, 4*p+3, toc(*(ch*)&v.w));
  }
  fft_ip<1,256>(A, t);                  // (Ln,Lw)*N
  const float sc = 1.0f/(float)NF;
  const size_t NSQ = (size_t)NF*NF;
#pragma unroll
  for (int u=0; u<8; ++u){
    int c = t + u*256;
    cplx Lv = lget(A, c);
    outF[base + c]       = sc*(Lv.x - adv[u].x);   // dn
    outF[NSQ + base + c] = sc*(Lv.y - adv[u].y);   // dw
  }
}

extern "C" void kernel_launch(void* const* d_in, const int* in_sizes, int n_in,
                              void* d_out, int out_size, void* d_ws, size_t ws_size,
                              hipStream_t stream) {
  const float* nIn = (const float*)d_in[0];
  const float* wIn = (const float*)d_in[1];
  float* outF = (float*)d_out;

  const size_t B  = (size_t)NF * NF * sizeof(cplx);    // 33.5 MB
  const size_t Bh = (size_t)NF * NF * sizeof(ch);      // 16.75 MB
  char* ws = (char*)d_ws;
  ch*   W    = (ch*)(ws);                   // slot0 (fp16)
  ch*   S1   = (ch*)(ws + 1*B);             // slot1 (later ADVt)
  ch*   S2   = (ch*)(ws + 1*B + Bh);
  ch*   S3   = (ch*)(ws + 2*B);             // slot2
  ch*   S4   = (ch*)(ws + 2*B + Bh);
  ch*   T1   = (ch*)(ws + 3*B);             // slot3
  ch*   T2   = (ch*)(ws + 3*B + Bh);
  ch*   T3   = (ch*)(ws + 4*B);             // slot4
  ch*   T4   = (ch*)(ws + 4*B + Bh);
  ch*   ADVt = (ch*)(ws + 1*B);             // slot1 (S1,S2 dead by then)
  ch*   BR   = (ch*)d_out;                  // scratch until k_final overwrites

  // forward pass 1 (along y) with transposed fp16 store
  k_fwd_pack_T <<<512, 512, 0, stream>>>(nIn, wIn, W);

  // forward pass 2 + unpack -> S1..S4 (fp16, 1/N)
  k_unpackS <<<1024, 512, 0, stream>>>(W, S1, S2, S3, S4);

  // ifft along kx + transposed fp16 store (fp16 LDS, 32KB, 4 blocks/CU)
  k_inv4 <<<dim3(512,4), 512, 0, stream>>>(S1, S2, S3, S4, T1, T2, T3, T4);

  // bracket -> BR [x][ky'] fp16 (masked rows skipped)
  k_bracket <<<NF, 256, 0, stream>>>(T1, T2, T3, BR);

  // fftX + dealias + ifftX fused (r16), transposed fp16 write -> ADVt
  k_slabX <<<512, 512, 0, stream>>>(BR, ADVt);

  // final: ifftY of ADVt & T4, combine -> d_out
  k_final <<<NF, 256, 0, stream>>>(ADVt, T4, outF);
}

// Round 17
// 159.497 us; speedup vs baseline: 1.0051x; 1.0051x over previous
//
#include <hip/hip_runtime.h>
#include <hip/hip_fp16.h>
#include <math.h>

// Hasegawa-Wakatani 2D RHS, 2048^2, all-spectral. FINAL = R15 (159.8us,
// measured best). R16's fp16-LDS inv4 reverted (neutral: bank conflicts +
// converts ate the LDS saving; occupancy unchanged -> latency-structural
// plateau confirmed per pre-committed test).
//
// Journey: 466 (R1 naive radix-2) -> 160 us via: radix-8 then radix-16,16,8
// Stockham cores; all transposes fused into FFT kernels (dense writer-side
// 16B segment stores + XCD-chunk healing); fp16 for every intermediate;
// dealias-aware compute/store skips; dispatch-count 22 -> 6.
//
// Pipeline (slots of 33.5MB in d_ws):
//  pack_T : n,w --fftY(r16), write^T--> W[ky][x] fp16            slot0
//  unpackS: W row --fftX(r8), unpack--> S1..S4 (fp16, 1/N)       slot1,2
//  inv4   : S_i --ifftX(r16), write^T--> T_i [x][ky] fp16        slot3,4
//  bracket: T1..T3 rows --4x fft(r8)--> BR fp16 (my-skip)        d_out
//  slabX  : BR --fftX(r16), mask/N, ifftX(r16), write^T--> ADVt  slot1
//  final  : ADVt,T4 rows --2x ifft(r8), combine--> dn,dw f32     d_out

#define NF 2048
#define HALF 1024
#define K0F 0.15f
#define DEAL_LIM 682

typedef float2 cplx;
typedef __half2 ch;

__device__ __forceinline__ ch toh(cplx v){ return __float22half2_rn(make_float2(v.x, v.y)); }
__device__ __forceinline__ cplx toc(ch h){ float2 f = __half22float2(h); return make_float2(f.x, f.y); }

__device__ __forceinline__ int sw(int i){ return i ^ ((i>>4)&15) ^ ((i>>8)&15); }
__device__ __forceinline__ cplx cmul(cplx a, cplx b){ return make_float2(a.x*b.x - a.y*b.y, a.x*b.y + a.y*b.x); }
__device__ __forceinline__ cplx cadd(cplx a, cplx b){ return make_float2(a.x+b.x, a.y+b.y); }
__device__ __forceinline__ cplx csub(cplx a, cplx b){ return make_float2(a.x-b.x, a.y-b.y); }
template<int SIGN> __device__ __forceinline__ cplx rot90(cplx z){
  return (SIGN>0)? make_float2(-z.y,z.x) : make_float2(z.y,-z.x); }
__device__ __forceinline__ void lput(cplx* L, int i, cplx v){ L[sw(i)] = v; }
__device__ __forceinline__ cplx lget(const cplx* L, int i){ return L[sw(i)]; }

__device__ __forceinline__ int xcd_chunk(int bid, int nwg){
  return (bid & 7) * (nwg >> 3) + (bid >> 3);
}

// ================= radix-8,8,8,4 core (TPR parametric) =====================
template<int SIGN, int TPR, int M>
__device__ __forceinline__ void stage8_ip(cplx* X, int t) {
  constexpr int BPT = 256 / TPR;
  const float ang = (float)SIGN * 0.0030679615757712824f; // 2*pi/2048
  cplx a[BPT][8];
#pragma unroll
  for (int u = 0; u < BPT; ++u) {
    const int b = t + u * TPR;
#pragma unroll
    for (int k = 0; k < 8; ++k) a[u][k] = X[sw(b + 256 * k)];
  }
  __syncthreads();
#pragma unroll
  for (int u = 0; u < BPT; ++u) {
    const int b = t + u * TPR;
    const int i = b & (M - 1);
    const int jm = b - i;
    cplx a0=a[u][0], a1=a[u][1], a2=a[u][2], a3=a[u][3],
         a4=a[u][4], a5=a[u][5], a6=a[u][6], a7=a[u][7];
    cplx t0=cadd(a0,a4), t1=csub(a0,a4), t2=cadd(a2,a6), t3=rot90<SIGN>(csub(a2,a6));
    cplx E0=cadd(t0,t2), E2=csub(t0,t2), E1=cadd(t1,t3), E3=csub(t1,t3);
    cplx u0=cadd(a1,a5), u1=csub(a1,a5), u2=cadd(a3,a7), u3=rot90<SIGN>(csub(a3,a7));
    cplx O0=cadd(u0,u2), O2=csub(u0,u2), O1=cadd(u1,u3), O3=csub(u1,u3);
    const float hh = 0.70710678118654752440f;
    O1 = cmul(O1, make_float2(hh, (float)SIGN*hh));
    O2 = rot90<SIGN>(O2);
    O3 = cmul(O3, make_float2(-hh, (float)SIGN*hh));
    cplx y0=cadd(E0,O0), y4=csub(E0,O0);
    cplx y1=cadd(E1,O1), y5=csub(E1,O1);
    cplx y2=cadd(E2,O2), y6=csub(E2,O2);
    cplx y3=cadd(E3,O3), y7=csub(E3,O3);
    float sn, cs;
    __sincosf(ang * (float)jm, &sn, &cs);
    cplx w1 = make_float2(cs, sn);
    cplx w2 = cmul(w1,w1), w3 = cmul(w2,w1), w4 = cmul(w2,w2);
    cplx w5 = cmul(w3,w2), w6 = cmul(w3,w3), w7 = cmul(w4,w3);
    const int o = 8*jm + i;
    X[sw(o)]       = y0;
    X[sw(o+M)]     = cmul(y1,w1);
    X[sw(o+2*M)]   = cmul(y2,w2);
    X[sw(o+3*M)]   = cmul(y3,w3);
    X[sw(o+4*M)]   = cmul(y4,w4);
    X[sw(o+5*M)]   = cmul(y5,w5);
    X[sw(o+6*M)]   = cmul(y6,w6);
    X[sw(o+7*M)]   = cmul(y7,w7);
  }
  __syncthreads();
}

template<int SIGN, int TPR>
__device__ __forceinline__ void stage4_ip(cplx* X, int t){
  constexpr int QPT = 512 / TPR;
  cplx a[QPT][4];
#pragma unroll
  for (int u=0; u<QPT; ++u){
    const int b = t + u*TPR;
#pragma unroll
    for (int k=0;k<4;++k) a[u][k] = X[sw(b + 512*k)];
  }
  __syncthreads();
#pragma unroll
  for (int u=0; u<QPT; ++u){
    const int b = t + u*TPR;
    cplx a0=a[u][0], a1=a[u][1], a2=a[u][2], a3=a[u][3];
    cplx t0=cadd(a0,a2), t1=csub(a0,a2), t2=cadd(a1,a3), t3=rot90<SIGN>(csub(a1,a3));
    X[sw(b)]       = cadd(t0,t2);
    X[sw(b+512)]   = cadd(t1,t3);
    X[sw(b+1024)]  = csub(t0,t2);
    X[sw(b+1536)]  = csub(t1,t3);
  }
  __syncthreads();
}

template<int SIGN, int TPR>
__device__ __forceinline__ void fft_ip(cplx* X, int t){
  __syncthreads();
  stage8_ip<SIGN,TPR,1>(X,t);
  stage8_ip<SIGN,TPR,8>(X,t);
  stage8_ip<SIGN,TPR,64>(X,t);
  stage4_ip<SIGN,TPR>(X,t);
}

// ================= radix-16,16,8 core (TPR=128 only, all lanes active) ====
template<int SIGN>
__device__ __forceinline__ void dft4(cplx& a0, cplx& a1, cplx& a2, cplx& a3){
  cplx t0=cadd(a0,a2), t1=csub(a0,a2), t2=cadd(a1,a3), t3=rot90<SIGN>(csub(a1,a3));
  a0=cadd(t0,t2); a1=cadd(t1,t3); a2=csub(t0,t2); a3=csub(t1,t3);
}

// 16-pt DFT via 4x4 DIT. In: a[n] natural. Out: y[q] at a[4*(q&3)+(q>>2)].
template<int SIGN>
__device__ __forceinline__ void dft16(cplx a[16]){
  dft4<SIGN>(a[0], a[4], a[8],  a[12]);
  dft4<SIGN>(a[1], a[5], a[9],  a[13]);
  dft4<SIGN>(a[2], a[6], a[10], a[14]);
  dft4<SIGN>(a[3], a[7], a[11], a[15]);
  const float c1 = 0.92387953251128675613f, s1v = 0.38268343236508977173f;
  const float hh = 0.70710678118654752440f;
  const cplx e1 = make_float2(c1,  (float)SIGN*s1v);   // w16^1
  const cplx e2 = make_float2(hh,  (float)SIGN*hh);    // w16^2
  const cplx e3 = make_float2(s1v, (float)SIGN*c1);    // w16^3
  const cplx e6 = make_float2(-hh, (float)SIGN*hh);    // w16^6
  a[5]  = cmul(a[5],  e1);
  a[6]  = cmul(a[6],  e2);
  a[7]  = cmul(a[7],  e3);
  a[9]  = cmul(a[9],  e2);
  a[10] = rot90<SIGN>(a[10]);
  a[11] = cmul(a[11], e6);
  a[13] = cmul(a[13], e3);
  a[14] = cmul(a[14], e6);
  { cplx m = cmul(a[15], e1); a[15] = make_float2(-m.x, -m.y); }
  dft4<SIGN>(a[0],  a[1],  a[2],  a[3]);
  dft4<SIGN>(a[4],  a[5],  a[6],  a[7]);
  dft4<SIGN>(a[8],  a[9],  a[10], a[11]);
  dft4<SIGN>(a[12], a[13], a[14], a[15]);
}

// radix-16 Stockham stage, 128 butterflies, t in 0..127 (one per lane).
template<int SIGN, int M>
__device__ __forceinline__ void stage16_ip(cplx* X, int t){
  const float ang = (float)SIGN * 0.0030679615757712824f; // 2*pi/2048
  cplx a[16];
#pragma unroll
  for (int k=0;k<16;++k) a[k] = X[sw(t + 128*k)];
  __syncthreads();
  dft16<SIGN>(a);
  const int i = t & (M-1);
  const int jm = t - i;
  float sn, cs;
  __sincosf(ang * (float)jm, &sn, &cs);
  cplx w1 = make_float2(cs, sn);
  cplx w2 = cmul(w1,w1),  w3 = cmul(w2,w1),  w4 = cmul(w2,w2);
  cplx w5 = cmul(w3,w2),  w6 = cmul(w3,w3),  w7 = cmul(w4,w3);
  cplx w8 = cmul(w4,w4),  w9 = cmul(w5,w4),  w10= cmul(w5,w5);
  cplx w11= cmul(w6,w5),  w12= cmul(w6,w6),  w13= cmul(w7,w6);
  cplx w14= cmul(w7,w7),  w15= cmul(w8,w7);
  const int o = 16*jm + i;
  X[sw(o)]      = a[0];
  X[sw(o+M)]    = cmul(a[4],  w1);
  X[sw(o+2*M)]  = cmul(a[8],  w2);
  X[sw(o+3*M)]  = cmul(a[12], w3);
  X[sw(o+4*M)]  = cmul(a[1],  w4);
  X[sw(o+5*M)]  = cmul(a[5],  w5);
  X[sw(o+6*M)]  = cmul(a[9],  w6);
  X[sw(o+7*M)]  = cmul(a[13], w7);
  X[sw(o+8*M)]  = cmul(a[2],  w8);
  X[sw(o+9*M)]  = cmul(a[6],  w9);
  X[sw(o+10*M)] = cmul(a[10], w10);
  X[sw(o+11*M)] = cmul(a[14], w11);
  X[sw(o+12*M)] = cmul(a[3],  w12);
  X[sw(o+13*M)] = cmul(a[7],  w13);
  X[sw(o+14*M)] = cmul(a[11], w14);
  X[sw(o+15*M)] = cmul(a[15], w15);
  __syncthreads();
}

// final radix-8 stage, m=256 (jm=0, twiddle-free), t in 0..127, 2 bfly/lane
template<int SIGN>
__device__ __forceinline__ void stage8_last16(cplx* X, int t){
  cplx a[2][8];
#pragma unroll
  for (int u=0; u<2; ++u){
    const int b = t + u*128;
#pragma unroll
    for (int k=0;k<8;++k) a[u][k] = X[sw(b + 256*k)];
  }
  __syncthreads();
#pragma unroll
  for (int u=0; u<2; ++u){
    const int b = t + u*128;
    cplx a0=a[u][0], a1=a[u][1], a2=a[u][2], a3=a[u][3],
         a4=a[u][4], a5=a[u][5], a6=a[u][6], a7=a[u][7];
    cplx t0=cadd(a0,a4), t1=csub(a0,a4), t2=cadd(a2,a6), t3=rot90<SIGN>(csub(a2,a6));
    cplx E0=cadd(t0,t2), E2=csub(t0,t2), E1=cadd(t1,t3), E3=csub(t1,t3);
    cplx u0=cadd(a1,a5), u1=csub(a1,a5), u2=cadd(a3,a7), u3=rot90<SIGN>(csub(a3,a7));
    cplx O0=cadd(u0,u2), O2=csub(u0,u2), O1=cadd(u1,u3), O3=csub(u1,u3);
    const float hh = 0.70710678118654752440f;
    O1 = cmul(O1, make_float2(hh, (float)SIGN*hh));
    O2 = rot90<SIGN>(O2);
    O3 = cmul(O3, make_float2(-hh, (float)SIGN*hh));
    X[sw(b)]       = cadd(E0,O0);
    X[sw(b+256)]   = cadd(E1,O1);
    X[sw(b+512)]   = cadd(E2,O2);
    X[sw(b+768)]   = cadd(E3,O3);
    X[sw(b+1024)]  = csub(E0,O0);
    X[sw(b+1280)]  = csub(E1,O1);
    X[sw(b+1536)]  = csub(E2,O2);
    X[sw(b+1792)]  = csub(E3,O3);
  }
  __syncthreads();
}

template<int SIGN>
__device__ __forceinline__ void fft16_ip(cplx* X, int t){
  __syncthreads();
  stage16_ip<SIGN,1>(X,t);
  stage16_ip<SIGN,16>(X,t);
  stage8_last16<SIGN>(X,t);
}

// ---- spectral unpack at one (kx,ky): a=F(ky,kx), b=F(-ky,-kx)
__device__ __forceinline__ void unpack_point(cplx a, cplx b,
    float kxv, float kyv, float kxp, float kyp,
    cplx& s1, cplx& s2, cplx& s3, cplx& s4) {
  cplx nh = make_float2(0.5f*(a.x + b.x),  0.5f*(a.y - b.y));
  cplx wh = make_float2(0.5f*(a.y + b.y), -0.5f*(a.x - b.x));
  float k2 = kxv*kxv + kyv*kyv;
  float pinv = (k2 > 1e-12f) ? (-1.0f/k2) : 0.0f;
  cplx ph = make_float2(wh.x*pinv, wh.y*pinv);
  s1 = make_float2(-kxp*ph.y - kyp*ph.x, kxp*ph.x - kyp*ph.y);
  s2 = make_float2(-kxp*nh.y - kyp*nh.x, kxp*nh.x - kyp*nh.y);
  s3 = make_float2(-kxp*wh.y - kyp*wh.x, kxp*wh.x - kyp*wh.y);
  float dnc = 0.001f * k2;
  cplx Ln = make_float2( kyp*ph.y + (ph.x - nh.x) - dnc*nh.x,
                        -kyp*ph.x + (ph.y - nh.y) - dnc*nh.y);
  cplx Lw = make_float2( kyp*nh.y + (ph.x - nh.x) - dnc*wh.x,
                        -kyp*nh.x + (ph.y - nh.y) - dnc*wh.y);
  s4 = make_float2(Ln.x - Lw.y, Ln.y + Lw.x);
}

// ---- kernels -------------------------------------------------------------

// 4 x-rows: load n,w, fft along y (r16), transposed fp16 store -> W[ky][x]
__global__ void __launch_bounds__(512) k_fwd_pack_T(const float* __restrict__ nIn,
                                                    const float* __restrict__ wIn,
                                                    ch* __restrict__ out) {
  __shared__ cplx L[4*NF];
  const int tid = threadIdx.x;
  const int lb = xcd_chunk(blockIdx.x, gridDim.x);
  const int xb = lb*4;
#pragma unroll
  for (int u=0; u<4; ++u){
    int f = tid + u*512;           // 0..2047
    int r = f >> 9;                // row 0..3
    int p = f & 511;               // float4 idx
    float4 nv = ((const float4*)(nIn + (size_t)(xb+r)*NF))[p];
    float4 wv = ((const float4*)(wIn + (size_t)(xb+r)*NF))[p];
    cplx* Lr = L + r*NF;
    lput(Lr, 4*p+0, make_float2(nv.x, wv.x));
    lput(Lr, 4*p+1, make_float2(nv.y, wv.y));
    lput(Lr, 4*p+2, make_float2(nv.z, wv.z));
    lput(Lr, 4*p+3, make_float2(nv.w, wv.w));
  }
  const int row = tid >> 7, t = tid & 127;
  fft16_ip<-1>(L + row*NF, t);
  uint4* o16 = (uint4*)out;        // fp16 row = 512 uint4
#pragma unroll
  for (int u=0; u<4; ++u){
    int ky = tid + u*512;          // 0..2047
    ch h0 = toh(lget(L + 0*NF, ky));
    ch h1 = toh(lget(L + 1*NF, ky));
    ch h2 = toh(lget(L + 2*NF, ky));
    ch h3 = toh(lget(L + 3*NF, ky));
    uint4 v;
    v.x = *(unsigned*)&h0; v.y = *(unsigned*)&h1;
    v.z = *(unsigned*)&h2; v.w = *(unsigned*)&h3;
    o16[(size_t)ky*(NF/4) + lb] = v;
  }
}

// rows kyA=b, kyB=(b==0?1024:2048-b): fftX (r8) both, unpack -> S1..S4 fp16
__global__ void __launch_bounds__(512) k_unpackS(const ch* __restrict__ in,
                                                 ch* __restrict__ S1, ch* __restrict__ S2,
                                                 ch* __restrict__ S3, ch* __restrict__ S4) {
  __shared__ cplx F0[NF], F1[NF];
  const int tid = threadIdx.x;
  const int b = xcd_chunk(blockIdx.x, gridDim.x);   // 0..1023
  const int kyA = b;
  const int kyB = (b == 0) ? HALF : NF - b;
  const int half = tid >> 8;
  const int t = tid & 255;
  cplx* Fm = half ? F1 : F0;
  {
    const ch* g = in + (size_t)(half ? kyB : kyA)*NF;
#pragma unroll
    for (int u=0; u<2; ++u){
      int p = t + u*256;           // uint4 idx, 512 per fp16 row
      uint4 v = ((const uint4*)g)[p];
      lput(Fm, 4*p+0, toc(*(ch*)&v.x));
      lput(Fm, 4*p+1, toc(*(ch*)&v.y));
      lput(Fm, 4*p+2, toc(*(ch*)&v.z));
      lput(Fm, 4*p+3, toc(*(ch*)&v.w));
    }
    fft_ip<-1,256>(Fm, t);
  }
  const cplx* Fp = (b == 0) ? (const cplx*)Fm : (half ? F0 : F1);
  const int kyM = half ? kyB : kyA;
  const int sy = (kyM < HALF) ? kyM : kyM - NF;
  const float kyv = K0F * (float)sy;
  const float kyp = (kyM == HALF) ? 0.0f : kyv;
  const float sc = 1.0f/(float)NF;
  const size_t rbase = (size_t)kyM * NF;
#pragma unroll
  for (int u=0; u<8; ++u){
    int kx = t + u*256;
    int kx2 = (NF - kx) & (NF - 1);
    int sx = (kx < HALF) ? kx : kx - NF;
    float kxv = K0F * (float)sx;
    float kxp = (kx == HALF) ? 0.0f : kxv;
    cplx s1,s2,s3,s4;
    unpack_point(lget(Fm,kx), lget(Fp,kx2), kxv, kyv, kxp, kyp, s1,s2,s3,s4);
    S1[rbase+kx] = toh(make_float2(sc*s1.x, sc*s1.y));
    S2[rbase+kx] = toh(make_float2(sc*s2.x, sc*s2.y));
    S3[rbase+kx] = toh(make_float2(sc*s3.x, sc*s3.y));
    S4[rbase+kx] = toh(make_float2(sc*s4.x, sc*s4.y));
  }
}

// 4 rows, one of 4 arrays (blockIdx.y): ifft (r16), transposed fp16 store.
__global__ void __launch_bounds__(512) k_inv4(const ch* __restrict__ S1, const ch* __restrict__ S2,
                                              const ch* __restrict__ S3, const ch* __restrict__ S4,
                                              ch* __restrict__ T1, ch* __restrict__ T2,
                                              ch* __restrict__ T3, ch* __restrict__ T4) {
  __shared__ cplx L[4*NF];
  const int tid = threadIdx.x;
  const int lb = xcd_chunk(blockIdx.x, gridDim.x);
  const ch* in; ch* out;
  if      (blockIdx.y == 0){ in = S1; out = T1; }
  else if (blockIdx.y == 1){ in = S2; out = T2; }
  else if (blockIdx.y == 2){ in = S3; out = T3; }
  else                     { in = S4; out = T4; }
  const int rb = lb*4;
#pragma unroll
  for (int u=0; u<4; ++u){
    int f = tid + u*512;           // 0..2047
    int r = f >> 9, p = f & 511;   // 512 uint4 per fp16 row
    uint4 v = ((const uint4*)(in + (size_t)(rb+r)*NF))[p];
    cplx* Lr = L + r*NF;
    lput(Lr, 4*p+0, toc(*(ch*)&v.x));
    lput(Lr, 4*p+1, toc(*(ch*)&v.y));
    lput(Lr, 4*p+2, toc(*(ch*)&v.z));
    lput(Lr, 4*p+3, toc(*(ch*)&v.w));
  }
  const int row = tid >> 7, t = tid & 127;
  fft16_ip<1>(L + row*NF, t);
  uint4* o16 = (uint4*)out;        // fp16 row = 512 uint4
#pragma unroll
  for (int u=0; u<4; ++u){
    int q = tid + u*512;           // output row (= x) 0..2047
    ch h0 = toh(lget(L + 0*NF, q));
    ch h1 = toh(lget(L + 1*NF, q));
    ch h2 = toh(lget(L + 2*NF, q));
    ch h3 = toh(lget(L + 3*NF, q));
    uint4 v;
    v.x = *(unsigned*)&h0; v.y = *(unsigned*)&h1;
    v.z = *(unsigned*)&h2; v.w = *(unsigned*)&h3;
    o16[(size_t)q*(NF/4) + lb] = v;
  }
}

// 1 x-row, 256 thr (r8): 3x ifft (dphi regs), bracket, fwd fft -> BR fp16
__global__ void __launch_bounds__(256) k_bracket(const ch* __restrict__ T1,
                                                 const ch* __restrict__ T2,
                                                 const ch* __restrict__ T3,
                                                 ch* __restrict__ out) {
  __shared__ cplx A[NF];
  const int t = threadIdx.x;
  const size_t base = (size_t)blockIdx.x * NF;
#pragma unroll
  for (int u=0; u<2; ++u){
    int p = t + u*256;
    uint4 v = ((const uint4*)(T1 + base))[p];
    lput(A, 4*p+0, toc(*(ch*)&v.x)); lput(A, 4*p+1, toc(*(ch*)&v.y));
    lput(A, 4*p+2, toc(*(ch*)&v.z)); lput(A, 4*p+3, toc(*(ch*)&v.w));
  }
  fft_ip<1,256>(A, t);                  // (dphix,dphiy)*N
  cplx dphi[8];
#pragma unroll
  for (int u=0; u<8; ++u) dphi[u] = lget(A, t + u*256);
  __syncthreads();
#pragma unroll
  for (int u=0; u<2; ++u){
    int p = t + u*256;
    uint4 v = ((const uint4*)(T2 + base))[p];
    lput(A, 4*p+0, toc(*(ch*)&v.x)); lput(A, 4*p+1, toc(*(ch*)&v.y));
    lput(A, 4*p+2, toc(*(ch*)&v.z)); lput(A, 4*p+3, toc(*(ch*)&v.w));
  }
  fft_ip<1,256>(A, t);                  // (dnx,dny)*N
  float jn[8];
#pragma unroll
  for (int u=0; u<8; ++u){
    cplx dd = lget(A, t + u*256);
    jn[u] = dphi[u].x*dd.y - dphi[u].y*dd.x;
  }
  __syncthreads();
#pragma unroll
  for (int u=0; u<2; ++u){
    int p = t + u*256;
    uint4 v = ((const uint4*)(T3 + base))[p];
    lput(A, 4*p+0, toc(*(ch*)&v.x)); lput(A, 4*p+1, toc(*(ch*)&v.y));
    lput(A, 4*p+2, toc(*(ch*)&v.z)); lput(A, 4*p+3, toc(*(ch*)&v.w));
  }
  fft_ip<1,256>(A, t);                  // (dwx,dwy)*N
  const float sc2 = 1.0f/((float)NF*(float)NF);
#pragma unroll
  for (int u=0; u<8; ++u){
    int c = t + u*256;
    cplx dd = lget(A, c);
    float jw = dphi[u].x*dd.y - dphi[u].y*dd.x;
    lput(A, c, make_float2(sc2*jn[u], sc2*jw));   // own-slot r/w
  }
  fft_ip<-1,256>(A, t);                 // fft(j_n + i*j_w) along y
  uint4* o16 = (uint4*)(out + base);
#pragma unroll
  for (int u=0; u<2; ++u){
    int p = t + u*256;                  // uint4 covers ky' 4p..4p+3
    if (p <= 170 || p >= 341) {         // skip fully-masked [684,1363]
      ch h0 = toh(lget(A, 4*p+0));
      ch h1 = toh(lget(A, 4*p+1));
      ch h2 = toh(lget(A, 4*p+2));
      ch h3 = toh(lget(A, 4*p+3));
      uint4 v;
      v.x = *(unsigned*)&h0; v.y = *(unsigned*)&h1;
      v.z = *(unsigned*)&h2; v.w = *(unsigned*)&h3;
      o16[p] = v;
    }
  }
}

// 4 ky'-columns: fftX(r16), 2/3 mask*(1/N), ifftX(r16), transposed fp16 write.
// Fully-masked slabs: nothing at all (final synthesizes their zeros).
__global__ void __launch_bounds__(512) k_slabX(const ch* __restrict__ in,
                                               ch* __restrict__ out) {
  __shared__ cplx L[4*NF];
  const int tid = threadIdx.x;
  const int lb = xcd_chunk(blockIdx.x, gridDim.x);
  const int cb = lb*4;
  if (cb >= 684 && cb <= 1360) return;  // masked: not written, not read
#pragma unroll
  for (int u=0; u<4; ++u){
    int x = tid + u*512;           // 0..2047
    uint4 v = *(const uint4*)(in + (size_t)x*NF + cb);
    lput(L + 0*NF, x, toc(*(ch*)&v.x));
    lput(L + 1*NF, x, toc(*(ch*)&v.y));
    lput(L + 2*NF, x, toc(*(ch*)&v.z));
    lput(L + 3*NF, x, toc(*(ch*)&v.w));
  }
  const int row = tid >> 7, t = tid & 127;
  fft16_ip<-1>(L + row*NF, t);
  const float sc = 1.0f/(float)NF;
#pragma unroll
  for (int v2=0; v2<16; ++v2){
    int g = tid + v2*512;          // 0..8191
    int c = g >> 11, kk = g & 2047;
    int ky = cb + c;
    int sy = (ky < HALF) ? ky : ky - NF;
    int sx = (kk < HALF) ? kk : kk - NF;
    float m = (((sy<0?-sy:sy) <= DEAL_LIM) && ((sx<0?-sx:sx) <= DEAL_LIM)) ? sc : 0.0f;
    cplx z = lget(L + c*NF, kk);
    lput(L + c*NF, kk, make_float2(m*z.x, m*z.y));   // own-slot r/w
  }
  fft16_ip<1>(L + row*NF, t);
#pragma unroll
  for (int u=0; u<4; ++u){
    int x = tid + u*512;
    ch h0 = toh(lget(L + 0*NF, x));
    ch h1 = toh(lget(L + 1*NF, x));
    ch h2 = toh(lget(L + 2*NF, x));
    ch h3 = toh(lget(L + 3*NF, x));
    uint4 v;
    v.x = *(unsigned*)&h0; v.y = *(unsigned*)&h1;
    v.z = *(unsigned*)&h2; v.w = *(unsigned*)&h3;
    *(uint4*)(out + (size_t)x*NF + cb) = v;
  }
}

// 1 x-row, 256 thr (r8): ifft ADVt (adv regs; zeros synthesized for the
// masked range), ifft T4, combine -> dn,dw (f32)
__global__ void __launch_bounds__(256) k_final(const ch* __restrict__ ADVt,
                                               const ch* __restrict__ T4,
                                               float* __restrict__ outF) {
  __shared__ cplx A[NF];
  const int t = threadIdx.x;
  const size_t base = (size_t)blockIdx.x * NF;
#pragma unroll
  for (int u=0; u<2; ++u){
    int p = t + u*256;
    if (p >= 171 && p <= 340) {         // ky' 684..1363: slabX wrote nothing
      cplx z = make_float2(0.f, 0.f);
      lput(A, 4*p+0, z); lput(A, 4*p+1, z);
      lput(A, 4*p+2, z); lput(A, 4*p+3, z);
    } else {
      uint4 v = ((const uint4*)(ADVt + base))[p];
      lput(A, 4*p+0, toc(*(ch*)&v.x)); lput(A, 4*p+1, toc(*(ch*)&v.y));
      lput(A, 4*p+2, toc(*(ch*)&v.z)); lput(A, 4*p+3, toc(*(ch*)&v.w));
    }
  }
  fft_ip<1,256>(A, t);                  // adv*N
  cplx adv[8];
#pragma unroll
  for (int u=0; u<8; ++u) adv[u] = lget(A, t + u*256);
  __syncthreads();
#pragma unroll
  for (int u=0; u<2; ++u){
    int p = t + u*256;
    uint4 v = ((const uint4*)(T4 + base))[p];
    lput(A, 4*p+0, toc(*(ch*)&v.x)); lput(A, 4*p+1, toc(*(ch*)&v.y));
    lput(A, 4*p+2, toc(*(ch*)&v.z)); lput(A, 4*p+3, toc(*(ch*)&v.w));
  }
  fft_ip<1,256>(A, t);                  // (Ln,Lw)*N
  const float sc = 1.0f/(float)NF;
  const size_t NSQ = (size_t)NF*NF;
#pragma unroll
  for (int u=0; u<8; ++u){
    int c = t + u*256;
    cplx Lv = lget(A, c);
    outF[base + c]       = sc*(Lv.x - adv[u].x);   // dn
    outF[NSQ + base + c] = sc*(Lv.y - adv[u].y);   // dw
  }
}

extern "C" void kernel_launch(void* const* d_in, const int* in_sizes, int n_in,
                              void* d_out, int out_size, void* d_ws, size_t ws_size,
                              hipStream_t stream) {
  const float* nIn = (const float*)d_in[0];
  const float* wIn = (const float*)d_in[1];
  float* outF = (float*)d_out;

  const size_t B  = (size_t)NF * NF * sizeof(cplx);    // 33.5 MB
  const size_t Bh = (size_t)NF * NF * sizeof(ch);      // 16.75 MB
  char* ws = (char*)d_ws;
  ch*   W    = (ch*)(ws);                   // slot0 (fp16)
  ch*   S1   = (ch*)(ws + 1*B);             // slot1 (later ADVt)
  ch*   S2   = (ch*)(ws + 1*B + Bh);
  ch*   S3   = (ch*)(ws + 2*B);             // slot2
  ch*   S4   = (ch*)(ws + 2*B + Bh);
  ch*   T1   = (ch*)(ws + 3*B);             // slot3
  ch*   T2   = (ch*)(ws + 3*B + Bh);
  ch*   T3   = (ch*)(ws + 4*B);             // slot4
  ch*   T4   = (ch*)(ws + 4*B + Bh);
  ch*   ADVt = (ch*)(ws + 1*B);             // slot1 (S1,S2 dead by then)
  ch*   BR   = (ch*)d_out;                  // scratch until k_final overwrites

  // forward pass 1 (along y) with transposed fp16 store
  k_fwd_pack_T <<<512, 512, 0, stream>>>(nIn, wIn, W);

  // forward pass 2 + unpack -> S1..S4 (fp16, 1/N)
  k_unpackS <<<1024, 512, 0, stream>>>(W, S1, S2, S3, S4);

  // ifft along kx + transposed fp16 store (all four arrays, one dispatch)
  k_inv4 <<<dim3(512,4), 512, 0, stream>>>(S1, S2, S3, S4, T1, T2, T3, T4);

  // bracket -> BR [x][ky'] fp16 (masked rows skipped)
  k_bracket <<<NF, 256, 0, stream>>>(T1, T2, T3, BR);

  // fftX + dealias + ifftX fused (r16), transposed fp16 write -> ADVt
  k_slabX <<<512, 512, 0, stream>>>(BR, ADVt);

  // final: ifftY of ADVt & T4, combine -> d_out
  k_final <<<NF, 256, 0, stream>>>(ADVt, T4, outF);
}